// Round 8
// baseline (199.563 us; speedup 1.0000x reference)
//
#include <hip/hip_runtime.h>
#include <math.h>

#define BB 32
#define SS 512
#define HH 256
#define TT 48
#define START_IDX 46
#define STOP_IDX 47

typedef __attribute__((ext_vector_type(8))) short short8;
typedef __attribute__((ext_vector_type(4))) float floatx4;

__device__ __forceinline__ float rfl(float x) {
    return __int_as_float(__builtin_amdgcn_readfirstlane(__float_as_int(x)));
}
__device__ __forceinline__ unsigned int bf16_rne(float x) {
    const unsigned int u = __float_as_uint(x);
    return (u + 0x7fffu + ((u >> 16) & 1u)) >> 16;
}
__device__ __forceinline__ float bf2f(unsigned short h) {
    return __uint_as_float(((unsigned int)h) << 16);
}

// ---------------------------------------------------------------------------
// Kernel 1 (R6-exact): exem = exp(f.w + b) via bf16 MFMA; block 0 also
//   prebuilds the E = exp(trans) B-frags into ws for the chunk kernel.
// ---------------------------------------------------------------------------
__global__ __launch_bounds__(256) void emission_kernel(
    const float* __restrict__ f, const float* __restrict__ w,
    const float* __restrict__ bias, const float* __restrict__ trans,
    unsigned short* __restrict__ exem, uint4* __restrict__ Ebuf)
{
    __shared__ __align__(16) char smem[50176];
    __shared__ float biaslds[TT];
    unsigned short* wb = (unsigned short*)smem;       // [256][50] bf16
    uint4* fragbuf = (uint4*)(smem + 25600);          // [24][64]
    float* fl = (float*)smem;                         // [64][132] (overlay)

    const int tid = threadIdx.x;

    if (blockIdx.x == 0 && tid < 64) {
        const int g = tid >> 4, cl = tid & 15;
#pragma unroll
        for (int kc = 0; kc < 2; ++kc)
#pragma unroll
            for (int nt = 0; nt < 3; ++nt) {
                unsigned int p[4];
#pragma unroll
                for (int h2 = 0; h2 < 4; ++h2) {
                    const int k = kc * 32 + g * 8 + 2 * h2;
                    const int n = nt * 16 + cl;
                    const float lo = (k     < TT) ? __expf(trans[k * TT + n])       : 0.f;
                    const float hi = (k + 1 < TT) ? __expf(trans[(k + 1) * TT + n]) : 0.f;
                    p[h2] = bf16_rne(lo) | (bf16_rne(hi) << 16);
                }
                Ebuf[(kc * 3 + nt) * 64 + tid] = make_uint4(p[0], p[1], p[2], p[3]);
            }
    }

    for (int idx = tid; idx < HH * TT; idx += 256) {
        const int r = idx / TT;
        const int c = idx - r * TT;
        wb[r * 50 + c] = (unsigned short)bf16_rne(w[idx]);
    }
    if (tid < TT) biaslds[tid] = bias[tid];
    __syncthreads();

    for (int idx = tid; idx < 24 * 64; idx += 256) {
        const int fb = idx >> 6;
        const int l  = idx & 63;
        const int kt = fb / 3;
        const int nt = fb - kt * 3;
        const int kbase = kt * 32 + (l >> 4) * 8;
        const int col   = nt * 16 + (l & 15);
        unsigned int p[4];
#pragma unroll
        for (int h2 = 0; h2 < 4; ++h2) {
            const unsigned int lo = wb[(kbase + 2 * h2)     * 50 + col];
            const unsigned int hi = wb[(kbase + 2 * h2 + 1) * 50 + col];
            p[h2] = lo | (hi << 16);
        }
        fragbuf[idx] = make_uint4(p[0], p[1], p[2], p[3]);
    }
    __syncthreads();

    const int lane = tid & 63, wv = tid >> 6, g = lane >> 4, cl = lane & 15;

    short8 Bf[24];
#pragma unroll
    for (int fb = 0; fb < 24; ++fb)
        Bf[fb] = __builtin_bit_cast(short8, fragbuf[fb * 64 + lane]);
    __syncthreads();   // frags in regs; smem free for f overlay

    const int row0 = blockIdx.x * 64;
    floatx4 acc0 = {0.f,0.f,0.f,0.f}, acc1 = {0.f,0.f,0.f,0.f}, acc2 = {0.f,0.f,0.f,0.f};

    const int lr = wv * 16 + cl;
#pragma unroll
    for (int h = 0; h < 2; ++h) {
#pragma unroll
        for (int it = 0; it < 8; ++it) {
            const int idx = tid + it * 256;
            const int r = idx >> 5, k4 = idx & 31;
            const float4 v = ((const float4*)f)[(size_t)(row0 + r) * 64 + h * 32 + k4];
            *(float4*)&fl[r * 132 + k4 * 4] = v;
        }
        __syncthreads();
#pragma unroll
        for (int kt = 0; kt < 4; ++kt) {
            const float4 v0 = *(const float4*)&fl[lr * 132 + kt * 32 + g * 8];
            const float4 v1 = *(const float4*)&fl[lr * 132 + kt * 32 + g * 8 + 4];
            const unsigned int a0 = bf16_rne(v0.x) | (bf16_rne(v0.y) << 16);
            const unsigned int a1 = bf16_rne(v0.z) | (bf16_rne(v0.w) << 16);
            const unsigned int a2 = bf16_rne(v1.x) | (bf16_rne(v1.y) << 16);
            const unsigned int a3 = bf16_rne(v1.z) | (bf16_rne(v1.w) << 16);
            const short8 Af = __builtin_bit_cast(short8, make_uint4(a0, a1, a2, a3));
            const int kg = h * 4 + kt;
            acc0 = __builtin_amdgcn_mfma_f32_16x16x32_bf16(Af, Bf[kg * 3 + 0], acc0, 0, 0, 0);
            acc1 = __builtin_amdgcn_mfma_f32_16x16x32_bf16(Af, Bf[kg * 3 + 1], acc1, 0, 0, 0);
            acc2 = __builtin_amdgcn_mfma_f32_16x16x32_bf16(Af, Bf[kg * 3 + 2], acc2, 0, 0, 0);
        }
        __syncthreads();
    }

    const int outrow0 = row0 + wv * 16 + g * 4;
    const int n = cl;
#pragma unroll
    for (int r = 0; r < 4; ++r) {
        unsigned short* e = exem + (size_t)(outrow0 + r) * TT;
        e[ 0 + n] = (unsigned short)bf16_rne(__expf(acc0[r] + biaslds[ 0 + n]));
        e[16 + n] = (unsigned short)bf16_rne(__expf(acc1[r] + biaslds[16 + n]));
        e[32 + n] = (unsigned short)bf16_rne(__expf(acc2[r] + biaslds[32 + n]));
    }
}

// ---------------------------------------------------------------------------
// Kernel 2: chunk products (R6 structure) + FUSED finalize. Each of the 32
//   chunk blocks of batch b increments cnt[b] (device-scope); the last
//   arriver runs the per-batch serial combine inline (threads 0..63),
//   overlapping finalizes with other batches' chunk tails.
// ---------------------------------------------------------------------------
__global__ __launch_bounds__(192) void chunk_finalize_kernel(
    const unsigned short* __restrict__ exem,   // [B*S, T] bf16
    const uint4* __restrict__ Ebuf,            // prebuilt E B-frags
    const float* __restrict__ trans,           // [T, T]
    const int*   __restrict__ lengths,
    const int*   __restrict__ tags,
    unsigned short* __restrict__ Qs,           // [B*32][48][64] bf16
    float* __restrict__ Ls3,                   // [B*32][3] logscale
    int*   __restrict__ cnt,                   // [B] completion counters
    float* __restrict__ out)                   // [B]
{
    __shared__ __align__(8)  unsigned short ebuf[16 * TT];
    __shared__ __align__(16) unsigned short abuf[3][17 * 56];
    __shared__ int lastflag;
    __shared__ float tlds[TT * TT];
    __shared__ __align__(16) unsigned short vlds[64];
    __shared__ float Lsl[96];
    __shared__ float falds[96];

    const int bc = blockIdx.x, b = bc >> 5, c = bc & 31;
    const int len = lengths[b];
    int nsteps = (len - 1) - (c << 4);
    if (nsteps > 16) nsteps = 16;

    const int tid = threadIdx.x;
    const int rb = tid >> 6, l = tid & 63, g = l >> 4, cl = l & 15;

    if (nsteps > 0) {   // block-uniform
        // stage 16 emission rows (1536 B, coalesced)
        {
            const unsigned int* src = (const unsigned int*)(exem + ((size_t)b * SS + (c << 4)) * TT);
            unsigned int* dst = (unsigned int*)ebuf;
            dst[tid] = src[tid];
            dst[tid + 192] = src[tid + 192];
        }
        uint4 Bf[2][3];
#pragma unroll
        for (int kc = 0; kc < 2; ++kc)
#pragma unroll
            for (int nt = 0; nt < 3; ++nt)
                Bf[kc][nt] = Ebuf[(kc * 3 + nt) * 64 + l];
        __syncthreads();

        floatx4 acc[3];
#pragma unroll
        for (int nt = 0; nt < 3; ++nt)
#pragma unroll
            for (int r = 0; r < 4; ++r)
                acc[nt][r] = (16 * rb + 4 * g + r == nt * 16 + cl) ? 1.f : 0.f;

        float ev[3];
#pragma unroll
        for (int nt = 0; nt < 3; ++nt) ev[nt] = bf2f(ebuf[nt * 16 + cl]);

        float Lrb = 0.f;
        unsigned short* aw = abuf[rb];

        for (int s = 0; s < nsteps; ++s) {
            float scale = 1.f;
            if (s == 8) {
                const float sig = rfl(acc[0][0]);
                Lrb = __logf(sig);
                scale = __builtin_amdgcn_rcpf(sig);
            }
            const float f0 = ev[0] * scale, f1 = ev[1] * scale, f2 = ev[2] * scale;
#pragma unroll
            for (int r = 0; r < 4; ++r) {
                const int rw = (4 * g + r) * 56;
                aw[rw +      cl] = (unsigned short)bf16_rne(acc[0][r] * f0);
                aw[rw + 16 + cl] = (unsigned short)bf16_rne(acc[1][r] * f1);
                aw[rw + 32 + cl] = (unsigned short)bf16_rne(acc[2][r] * f2);
            }
            if (s + 1 < nsteps) {
#pragma unroll
                for (int nt = 0; nt < 3; ++nt)
                    ev[nt] = bf2f(ebuf[(s + 1) * TT + nt * 16 + cl]);
            }
            uint4 a0 = *(const uint4*)&aw[cl * 56 + g * 8];
            uint4 a1 = *(const uint4*)&aw[cl * 56 + 32 + g * 8];
            if (g >= 2) a1 = make_uint4(0, 0, 0, 0);
            const floatx4 z = {0.f, 0.f, 0.f, 0.f};
#pragma unroll
            for (int nt = 0; nt < 3; ++nt) {
                floatx4 d = __builtin_amdgcn_mfma_f32_16x16x32_bf16(
                    __builtin_bit_cast(short8, a0), __builtin_bit_cast(short8, Bf[0][nt]), z, 0, 0, 0);
                d = __builtin_amdgcn_mfma_f32_16x16x32_bf16(
                    __builtin_bit_cast(short8, a1), __builtin_bit_cast(short8, Bf[1][nt]), d, 0, 0, 0);
                acc[nt] = d;
            }
        }

        unsigned short* qb = Qs + (size_t)bc * (TT * 64);
#pragma unroll
        for (int nt = 0; nt < 3; ++nt) {
            const unsigned int lo = bf16_rne(acc[nt][0]) | (bf16_rne(acc[nt][1]) << 16);
            const unsigned int hi = bf16_rne(acc[nt][2]) | (bf16_rne(acc[nt][3]) << 16);
            *(uint2*)&qb[(nt * 16 + cl) * 64 + 16 * rb + 4 * g] = make_uint2(lo, hi);
        }
        if (l == 0) Ls3[bc * 3 + rb] = Lrb;
    }

    // ---- completion protocol: last arriver for batch b finalizes ----
    __threadfence();                 // release Qs/Ls3 (device scope)
    if (tid == 0) {
        const int old = atomicAdd(&cnt[b], 1);
        lastflag = (old == 31);
    }
    __syncthreads();
    if (!lastflag) return;
    __threadfence();                 // acquire other blocks' Qs/Ls3
    if (tid >= 64) return;

    // =================== finalize for batch b (wave 0) ===================
    for (int idx = l; idx < TT * TT; idx += 64) tlds[idx] = trans[idx];

    const int nc = (len - 1 + 15) >> 4;
    for (int i = l; i < nc * 3; i += 64) Lsl[i] = Ls3[b * 96 + i];
    __builtin_amdgcn_wave_barrier();
    for (int i = l; i < nc * 3; i += 64)
        falds[i] = __expf(Lsl[i] - Lsl[(i / 3) * 3]);
    __builtin_amdgcn_wave_barrier();

    // gold path score
    float gold = 0.f;
    for (int s = l; s < len; s += 64) {
        const int tag  = tags[b * SS + s];
        const int from = (s == 0) ? START_IDX : tags[b * SS + s - 1];
        gold += __logf(bf2f(exem[((size_t)b * SS + s) * TT + tag])) + tlds[from * TT + tag];
    }
    gold += __shfl_xor(gold, 32); gold += __shfl_xor(gold, 16); gold += __shfl_xor(gold, 8);
    gold += __shfl_xor(gold, 4);  gold += __shfl_xor(gold, 2);  gold += __shfl_xor(gold, 1);

    // v init: E[START,:] with chunk-0 rowblock factors folded in
    const float R0 = Lsl[0];
    float vj = 0.f;
    if (l < TT) vj = __expf(tlds[START_IDX * TT + l]) * falds[l >> 4];
    vlds[l] = (unsigned short)bf16_rne(vj);   // l>=48 -> 0 (k-pad)
    float L = R0;

    const unsigned short* qbase = Qs + (size_t)(b * 32) * (TT * 64);
    floatx4 accn[3];
    float inv = 1.f;

    uint4 pB0[3], pB1[3];
#pragma unroll
    for (int nt = 0; nt < 3; ++nt) {
        pB0[nt] = *(const uint4*)&qbase[(nt * 16 + cl) * 64 + g * 8];
        pB1[nt] = *(const uint4*)&qbase[(nt * 16 + cl) * 64 + 32 + g * 8];
    }

    for (int cc = 0; cc < nc; ++cc) {
        uint4 B0[3], B1[3];
#pragma unroll
        for (int nt = 0; nt < 3; ++nt) { B0[nt] = pB0[nt]; B1[nt] = pB1[nt]; }

        const int cn = (cc + 1 < nc) ? cc + 1 : cc;
#pragma unroll
        for (int nt = 0; nt < 3; ++nt) {
            pB0[nt] = *(const uint4*)&qbase[(size_t)cn * TT * 64 + (nt * 16 + cl) * 64 + g * 8];
            pB1[nt] = *(const uint4*)&qbase[(size_t)cn * TT * 64 + (nt * 16 + cl) * 64 + 32 + g * 8];
        }
#pragma unroll
        for (int nt = 0; nt < 3; ++nt)
            if (g >= 2) B1[nt] = make_uint4(0, 0, 0, 0);

        const uint4 A0 = *(const uint4*)&vlds[g * 8];
        const uint4 A1 = *(const uint4*)&vlds[32 + g * 8];

        const floatx4 z = {0.f, 0.f, 0.f, 0.f};
#pragma unroll
        for (int nt = 0; nt < 3; ++nt) {
            floatx4 d = __builtin_amdgcn_mfma_f32_16x16x32_bf16(
                __builtin_bit_cast(short8, A0), __builtin_bit_cast(short8, B0[nt]), z, 0, 0, 0);
            d = __builtin_amdgcn_mfma_f32_16x16x32_bf16(
                __builtin_bit_cast(short8, A1), __builtin_bit_cast(short8, B1[nt]), d, 0, 0, 0);
            accn[nt] = d;
        }

        const float sig = rfl(accn[0][0]);
        inv = __builtin_amdgcn_rcpf(sig);

        if (cc + 1 < nc) {
            const float Rn  = Lsl[(cc + 1) * 3];
            const float fa1 = falds[(cc + 1) * 3 + 1];
            const float fa2 = falds[(cc + 1) * 3 + 2];
            L += __logf(sig) + Rn;
            if (l < 16) {   // fa0 == 1
                vlds[ 0 + l] = (unsigned short)bf16_rne(accn[0][0] * inv);
                vlds[16 + l] = (unsigned short)bf16_rne(accn[1][0] * inv * fa1);
                vlds[32 + l] = (unsigned short)bf16_rne(accn[2][0] * inv * fa2);
            }
        } else {
            L += __logf(sig);
        }
    }

    // terminal: sum_n v[n] * exem[len-1][n] * exp(trans[n][STOP])
    float term = 0.f;
    if (l < 16) {
        const size_t erow = ((size_t)b * SS + (len - 1)) * TT;
#pragma unroll
        for (int nt = 0; nt < 3; ++nt) {
            const int col = nt * 16 + l;
            term += accn[nt][0] * inv * bf2f(exem[erow + col])
                    * __expf(tlds[col * TT + STOP_IDX]);
        }
    }
    term += __shfl_xor(term, 32); term += __shfl_xor(term, 16); term += __shfl_xor(term, 8);
    term += __shfl_xor(term, 4);  term += __shfl_xor(term, 2);  term += __shfl_xor(term, 1);

    if (l == 0) {
        const float all_paths = __logf(term) + L;
        const int last = tags[b * SS + len - 1];
        out[b] = all_paths - (gold + tlds[last * TT + STOP_IDX]);
    }
}

// ---------------------------------------------------------------------------
extern "C" void kernel_launch(void* const* d_in, const int* in_sizes, int n_in,
                              void* d_out, int out_size, void* d_ws, size_t ws_size,
                              hipStream_t stream) {
    const float* f       = (const float*)d_in[0];
    const float* w       = (const float*)d_in[1];
    const float* bias    = (const float*)d_in[2];
    const float* trans   = (const float*)d_in[3];
    const int*   lengths = (const int*)d_in[4];
    const int*   tags    = (const int*)d_in[5];
    float*       out     = (float*)d_out;

    // ws: exem bf16 | Qs bf16 | Ls3 f32 | Ebuf | cnt
    char* ws = (char*)d_ws;
    unsigned short* exem = (unsigned short*)ws;                  // 1,572,864 B
    unsigned short* Qs   = (unsigned short*)(ws + 1572864);      // 6,291,456 B
    float*          Lsc  = (float*)(ws + 7864320);               // 12,288 B
    uint4*          Ebuf = (uint4*)(ws + 7876608);               // 6,144 B
    int*            cnt  = (int*)(ws + 7882752);                 // 128 B

    hipMemsetAsync(cnt, 0, BB * sizeof(int), stream);
    emission_kernel<<<(BB * SS) / 64, 256, 0, stream>>>(f, w, bias, trans, exem, Ebuf);
    chunk_finalize_kernel<<<BB * 32, 192, 0, stream>>>(exem, Ebuf, trans, lengths, tags,
                                                       Qs, Lsc, cnt, out);
}

// Round 9
// 125.584 us; speedup vs baseline: 1.5891x; 1.5891x over previous
//
#include <hip/hip_runtime.h>
#include <math.h>

#define BB 32
#define SS 512
#define HH 256
#define TT 48
#define START_IDX 46
#define STOP_IDX 47

typedef __attribute__((ext_vector_type(8))) short short8;
typedef __attribute__((ext_vector_type(4))) float floatx4;

__device__ __forceinline__ float rfl(float x) {
    return __int_as_float(__builtin_amdgcn_readfirstlane(__float_as_int(x)));
}
__device__ __forceinline__ unsigned int bf16_rne(float x) {
    const unsigned int u = __float_as_uint(x);
    return (u + 0x7fffu + ((u >> 16) & 1u)) >> 16;
}
__device__ __forceinline__ float bf2f(unsigned short h) {
    return __uint_as_float(((unsigned int)h) << 16);
}

// ---------------------------------------------------------------------------
// Kernel 1 (R6-exact): exem = exp(f.w + b) via bf16 MFMA; block 0 also
//   prebuilds the E = exp(trans) B-frags into ws for the chunk kernel.
// ---------------------------------------------------------------------------
__global__ __launch_bounds__(256) void emission_kernel(
    const float* __restrict__ f, const float* __restrict__ w,
    const float* __restrict__ bias, const float* __restrict__ trans,
    unsigned short* __restrict__ exem, uint4* __restrict__ Ebuf)
{
    __shared__ __align__(16) char smem[50176];
    __shared__ float biaslds[TT];
    unsigned short* wb = (unsigned short*)smem;       // [256][50] bf16
    uint4* fragbuf = (uint4*)(smem + 25600);          // [24][64]
    float* fl = (float*)smem;                         // [64][132] (overlay)

    const int tid = threadIdx.x;

    if (blockIdx.x == 0 && tid < 64) {
        const int g = tid >> 4, cl = tid & 15;
#pragma unroll
        for (int kc = 0; kc < 2; ++kc)
#pragma unroll
            for (int nt = 0; nt < 3; ++nt) {
                unsigned int p[4];
#pragma unroll
                for (int h2 = 0; h2 < 4; ++h2) {
                    const int k = kc * 32 + g * 8 + 2 * h2;
                    const int n = nt * 16 + cl;
                    const float lo = (k     < TT) ? __expf(trans[k * TT + n])       : 0.f;
                    const float hi = (k + 1 < TT) ? __expf(trans[(k + 1) * TT + n]) : 0.f;
                    p[h2] = bf16_rne(lo) | (bf16_rne(hi) << 16);
                }
                Ebuf[(kc * 3 + nt) * 64 + tid] = make_uint4(p[0], p[1], p[2], p[3]);
            }
    }

    for (int idx = tid; idx < HH * TT; idx += 256) {
        const int r = idx / TT;
        const int c = idx - r * TT;
        wb[r * 50 + c] = (unsigned short)bf16_rne(w[idx]);
    }
    if (tid < TT) biaslds[tid] = bias[tid];
    __syncthreads();

    for (int idx = tid; idx < 24 * 64; idx += 256) {
        const int fb = idx >> 6;
        const int l  = idx & 63;
        const int kt = fb / 3;
        const int nt = fb - kt * 3;
        const int kbase = kt * 32 + (l >> 4) * 8;
        const int col   = nt * 16 + (l & 15);
        unsigned int p[4];
#pragma unroll
        for (int h2 = 0; h2 < 4; ++h2) {
            const unsigned int lo = wb[(kbase + 2 * h2)     * 50 + col];
            const unsigned int hi = wb[(kbase + 2 * h2 + 1) * 50 + col];
            p[h2] = lo | (hi << 16);
        }
        fragbuf[idx] = make_uint4(p[0], p[1], p[2], p[3]);
    }
    __syncthreads();

    const int lane = tid & 63, wv = tid >> 6, g = lane >> 4, cl = lane & 15;

    short8 Bf[24];
#pragma unroll
    for (int fb = 0; fb < 24; ++fb)
        Bf[fb] = __builtin_bit_cast(short8, fragbuf[fb * 64 + lane]);
    __syncthreads();   // frags in regs; smem free for f overlay

    const int row0 = blockIdx.x * 64;
    floatx4 acc0 = {0.f,0.f,0.f,0.f}, acc1 = {0.f,0.f,0.f,0.f}, acc2 = {0.f,0.f,0.f,0.f};

    const int lr = wv * 16 + cl;
#pragma unroll
    for (int h = 0; h < 2; ++h) {
#pragma unroll
        for (int it = 0; it < 8; ++it) {
            const int idx = tid + it * 256;
            const int r = idx >> 5, k4 = idx & 31;
            const float4 v = ((const float4*)f)[(size_t)(row0 + r) * 64 + h * 32 + k4];
            *(float4*)&fl[r * 132 + k4 * 4] = v;
        }
        __syncthreads();
#pragma unroll
        for (int kt = 0; kt < 4; ++kt) {
            const float4 v0 = *(const float4*)&fl[lr * 132 + kt * 32 + g * 8];
            const float4 v1 = *(const float4*)&fl[lr * 132 + kt * 32 + g * 8 + 4];
            const unsigned int a0 = bf16_rne(v0.x) | (bf16_rne(v0.y) << 16);
            const unsigned int a1 = bf16_rne(v0.z) | (bf16_rne(v0.w) << 16);
            const unsigned int a2 = bf16_rne(v1.x) | (bf16_rne(v1.y) << 16);
            const unsigned int a3 = bf16_rne(v1.z) | (bf16_rne(v1.w) << 16);
            const short8 Af = __builtin_bit_cast(short8, make_uint4(a0, a1, a2, a3));
            const int kg = h * 4 + kt;
            acc0 = __builtin_amdgcn_mfma_f32_16x16x32_bf16(Af, Bf[kg * 3 + 0], acc0, 0, 0, 0);
            acc1 = __builtin_amdgcn_mfma_f32_16x16x32_bf16(Af, Bf[kg * 3 + 1], acc1, 0, 0, 0);
            acc2 = __builtin_amdgcn_mfma_f32_16x16x32_bf16(Af, Bf[kg * 3 + 2], acc2, 0, 0, 0);
        }
        __syncthreads();
    }

    const int outrow0 = row0 + wv * 16 + g * 4;
    const int n = cl;
#pragma unroll
    for (int r = 0; r < 4; ++r) {
        unsigned short* e = exem + (size_t)(outrow0 + r) * TT;
        e[ 0 + n] = (unsigned short)bf16_rne(__expf(acc0[r] + biaslds[ 0 + n]));
        e[16 + n] = (unsigned short)bf16_rne(__expf(acc1[r] + biaslds[16 + n]));
        e[32 + n] = (unsigned short)bf16_rne(__expf(acc2[r] + biaslds[32 + n]));
    }
}

// ---------------------------------------------------------------------------
// Kernel 2 (R6-exact): chunk products Q_c = PROD(D_t*E), 16 steps/chunk,
//   rows split 16/wave across 3 waves, per-rowblock normalization at step 8.
// ---------------------------------------------------------------------------
__global__ __launch_bounds__(192) void chunk_kernel(
    const unsigned short* __restrict__ exem,   // [B*S, T] bf16
    const uint4* __restrict__ Ebuf,            // prebuilt E B-frags
    const int*   __restrict__ lengths,
    unsigned short* __restrict__ Qs,           // [B*32][48][64] bf16 (col-major Q)
    float* __restrict__ Ls3)                   // [B*32][3] per-rowblock logscale
{
    __shared__ __align__(8)  unsigned short ebuf[16 * TT];
    __shared__ __align__(16) unsigned short abuf[3][17 * 56];

    const int bc = blockIdx.x, b = bc >> 5, c = bc & 31;
    const int len = lengths[b];
    int nsteps = (len - 1) - (c << 4);
    if (nsteps <= 0) return;
    if (nsteps > 16) nsteps = 16;

    const int tid = threadIdx.x;
    const int rb = tid >> 6, l = tid & 63, g = l >> 4, cl = l & 15;

    {
        const unsigned int* src = (const unsigned int*)(exem + ((size_t)b * SS + (c << 4)) * TT);
        unsigned int* dst = (unsigned int*)ebuf;
        dst[tid] = src[tid];
        dst[tid + 192] = src[tid + 192];
    }

    uint4 Bf[2][3];
#pragma unroll
    for (int kc = 0; kc < 2; ++kc)
#pragma unroll
        for (int nt = 0; nt < 3; ++nt)
            Bf[kc][nt] = Ebuf[(kc * 3 + nt) * 64 + l];

    __syncthreads();

    floatx4 acc[3];
#pragma unroll
    for (int nt = 0; nt < 3; ++nt)
#pragma unroll
        for (int r = 0; r < 4; ++r)
            acc[nt][r] = (16 * rb + 4 * g + r == nt * 16 + cl) ? 1.f : 0.f;

    float ev[3];
#pragma unroll
    for (int nt = 0; nt < 3; ++nt) ev[nt] = bf2f(ebuf[nt * 16 + cl]);

    float Lrb = 0.f;
    unsigned short* aw = abuf[rb];

    for (int s = 0; s < nsteps; ++s) {
        float scale = 1.f;
        if (s == 8) {   // one normalization mid-chunk
            const float sig = rfl(acc[0][0]);
            Lrb = __logf(sig);
            scale = __builtin_amdgcn_rcpf(sig);
        }
        const float f0 = ev[0] * scale, f1 = ev[1] * scale, f2 = ev[2] * scale;
#pragma unroll
        for (int r = 0; r < 4; ++r) {
            const int rw = (4 * g + r) * 56;
            aw[rw +      cl] = (unsigned short)bf16_rne(acc[0][r] * f0);
            aw[rw + 16 + cl] = (unsigned short)bf16_rne(acc[1][r] * f1);
            aw[rw + 32 + cl] = (unsigned short)bf16_rne(acc[2][r] * f2);
        }
        if (s + 1 < nsteps) {
#pragma unroll
            for (int nt = 0; nt < 3; ++nt)
                ev[nt] = bf2f(ebuf[(s + 1) * TT + nt * 16 + cl]);
        }
        uint4 a0 = *(const uint4*)&aw[cl * 56 + g * 8];
        uint4 a1 = *(const uint4*)&aw[cl * 56 + 32 + g * 8];
        if (g >= 2) a1 = make_uint4(0, 0, 0, 0);   // k >= 48 pad
        const floatx4 z = {0.f, 0.f, 0.f, 0.f};
#pragma unroll
        for (int nt = 0; nt < 3; ++nt) {
            floatx4 d = __builtin_amdgcn_mfma_f32_16x16x32_bf16(
                __builtin_bit_cast(short8, a0), __builtin_bit_cast(short8, Bf[0][nt]), z, 0, 0, 0);
            d = __builtin_amdgcn_mfma_f32_16x16x32_bf16(
                __builtin_bit_cast(short8, a1), __builtin_bit_cast(short8, Bf[1][nt]), d, 0, 0, 0);
            acc[nt] = d;
        }
    }

    unsigned short* qb = Qs + (size_t)bc * (TT * 64);
#pragma unroll
    for (int nt = 0; nt < 3; ++nt) {
        const unsigned int lo = bf16_rne(acc[nt][0]) | (bf16_rne(acc[nt][1]) << 16);
        const unsigned int hi = bf16_rne(acc[nt][2]) | (bf16_rne(acc[nt][3]) << 16);
        *(uint2*)&qb[(nt * 16 + cl) * 64 + 16 * rb + 4 * g] = make_uint2(lo, hi);
    }
    if (l == 0) Ls3[bc * 3 + rb] = Lrb;
}

// ---------------------------------------------------------------------------
// Kernel 3: per-batch combine. Changes vs R6: distance-2 prefetch of chunk
//   B-frags (covers cross-XCD L2-miss latency ~600-900 cyc) and the
//   reconciliation expf factors hoisted out of the serial loop (fa0==1).
// ---------------------------------------------------------------------------
__global__ __launch_bounds__(64) void finalize_kernel(
    const unsigned short* __restrict__ exem,
    const float* __restrict__ trans,
    const int*   __restrict__ lengths,
    const int*   __restrict__ tags,
    const unsigned short* __restrict__ Qs,
    const float* __restrict__ Ls3,
    float* __restrict__ out)
{
    __shared__ float tlds[TT * TT];
    __shared__ __align__(16) unsigned short vlds[64];
    __shared__ float Lsl[96];
    __shared__ float falds[96];

    const int j = threadIdx.x, b = blockIdx.x, g = j >> 4, cl = j & 15;

    for (int idx = j; idx < TT * TT; idx += 64) tlds[idx] = trans[idx];

    const int len = lengths[b];
    const int nc = (len - 1 + 15) >> 4;
    for (int i = j; i < nc * 3; i += 64) Lsl[i] = Ls3[b * 96 + i];
    __builtin_amdgcn_wave_barrier();
    for (int i = j; i < nc * 3; i += 64)
        falds[i] = __expf(Lsl[i] - Lsl[(i / 3) * 3]);   // per chunk/rowblock
    __builtin_amdgcn_wave_barrier();

    // gold path score
    float gold = 0.f;
    for (int s = j; s < len; s += 64) {
        const int tag  = tags[b * SS + s];
        const int from = (s == 0) ? START_IDX : tags[b * SS + s - 1];
        gold += __logf(bf2f(exem[((size_t)b * SS + s) * TT + tag])) + tlds[from * TT + tag];
    }
    gold += __shfl_xor(gold, 32); gold += __shfl_xor(gold, 16); gold += __shfl_xor(gold, 8);
    gold += __shfl_xor(gold, 4);  gold += __shfl_xor(gold, 2);  gold += __shfl_xor(gold, 1);

    // v init: E[START,:] with chunk-0 rowblock factors folded in
    const float R0 = Lsl[0];
    float vj = 0.f;
    if (j < TT) vj = __expf(tlds[START_IDX * TT + j]) * falds[j >> 4];
    vlds[j] = (unsigned short)bf16_rne(vj);   // j>=48 -> 0 (k-pad)
    float L = R0;

    const unsigned short* qbase = Qs + (size_t)(b * 32) * (TT * 64);
    floatx4 accn[3];
    float inv = 1.f;

    // distance-2 prefetch: slot ring of 2 (48 VGPRs, free at 1 wave/block)
    uint4 P0[2][3], P1[2][3];
#pragma unroll
    for (int sl = 0; sl < 2; ++sl) {
        const int cc = (sl < nc) ? sl : (nc - 1);
#pragma unroll
        for (int nt = 0; nt < 3; ++nt) {
            P0[sl][nt] = *(const uint4*)&qbase[(size_t)cc * TT * 64 + (nt * 16 + cl) * 64 + g * 8];
            P1[sl][nt] = *(const uint4*)&qbase[(size_t)cc * TT * 64 + (nt * 16 + cl) * 64 + 32 + g * 8];
        }
    }

    for (int cc = 0; cc < nc; ++cc) {
        const int sl = cc & 1;
        uint4 B0[3], B1[3];
#pragma unroll
        for (int nt = 0; nt < 3; ++nt) { B0[nt] = P0[sl][nt]; B1[nt] = P1[sl][nt]; }

        // refill this slot with chunk cc+2 (clamped)
        const int cn = (cc + 2 < nc) ? cc + 2 : (nc - 1);
#pragma unroll
        for (int nt = 0; nt < 3; ++nt) {
            P0[sl][nt] = *(const uint4*)&qbase[(size_t)cn * TT * 64 + (nt * 16 + cl) * 64 + g * 8];
            P1[sl][nt] = *(const uint4*)&qbase[(size_t)cn * TT * 64 + (nt * 16 + cl) * 64 + 32 + g * 8];
        }

#pragma unroll
        for (int nt = 0; nt < 3; ++nt)
            if (g >= 2) B1[nt] = make_uint4(0, 0, 0, 0);   // k >= 48 pad

        const uint4 A0 = *(const uint4*)&vlds[g * 8];
        const uint4 A1 = *(const uint4*)&vlds[32 + g * 8];

        const floatx4 z = {0.f, 0.f, 0.f, 0.f};
#pragma unroll
        for (int nt = 0; nt < 3; ++nt) {
            floatx4 d = __builtin_amdgcn_mfma_f32_16x16x32_bf16(
                __builtin_bit_cast(short8, A0), __builtin_bit_cast(short8, B0[nt]), z, 0, 0, 0);
            d = __builtin_amdgcn_mfma_f32_16x16x32_bf16(
                __builtin_bit_cast(short8, A1), __builtin_bit_cast(short8, B1[nt]), d, 0, 0, 0);
            accn[nt] = d;
        }

        const float sig = rfl(accn[0][0]);   // > 0 always
        inv = __builtin_amdgcn_rcpf(sig);

        if (cc + 1 < nc) {
            const float Rn  = Lsl[(cc + 1) * 3];
            const float fa1 = falds[(cc + 1) * 3 + 1];
            const float fa2 = falds[(cc + 1) * 3 + 2];
            L += __logf(sig) + Rn;
            if (j < 16) {   // row 0 of result: lanes 0..15, reg 0; fa0 == 1
                vlds[ 0 + j] = (unsigned short)bf16_rne(accn[0][0] * inv);
                vlds[16 + j] = (unsigned short)bf16_rne(accn[1][0] * inv * fa1);
                vlds[32 + j] = (unsigned short)bf16_rne(accn[2][0] * inv * fa2);
            }
        } else {
            L += __logf(sig);
        }
    }

    // terminal: sum_n v[n] * exem[len-1][n] * exp(trans[n][STOP])
    float term = 0.f;
    if (j < 16) {
        const size_t erow = ((size_t)b * SS + (len - 1)) * TT;
#pragma unroll
        for (int nt = 0; nt < 3; ++nt) {
            const int col = nt * 16 + j;
            term += accn[nt][0] * inv * bf2f(exem[erow + col])
                    * __expf(tlds[col * TT + STOP_IDX]);
        }
    }
    term += __shfl_xor(term, 32); term += __shfl_xor(term, 16); term += __shfl_xor(term, 8);
    term += __shfl_xor(term, 4);  term += __shfl_xor(term, 2);  term += __shfl_xor(term, 1);

    if (j == 0) {
        const float all_paths = __logf(term) + L;
        const int last = tags[b * SS + len - 1];
        out[b] = all_paths - (gold + tlds[last * TT + STOP_IDX]);
    }
}

// ---------------------------------------------------------------------------
extern "C" void kernel_launch(void* const* d_in, const int* in_sizes, int n_in,
                              void* d_out, int out_size, void* d_ws, size_t ws_size,
                              hipStream_t stream) {
    const float* f       = (const float*)d_in[0];
    const float* w       = (const float*)d_in[1];
    const float* bias    = (const float*)d_in[2];
    const float* trans   = (const float*)d_in[3];
    const int*   lengths = (const int*)d_in[4];
    const int*   tags    = (const int*)d_in[5];
    float*       out     = (float*)d_out;

    // ws: exem bf16 | Qs bf16 | Ls3 f32 | Ebuf
    char* ws = (char*)d_ws;
    unsigned short* exem = (unsigned short*)ws;                  // 1,572,864 B
    unsigned short* Qs   = (unsigned short*)(ws + 1572864);      // 6,291,456 B
    float*          Lsc  = (float*)(ws + 7864320);               // 12,288 B
    uint4*          Ebuf = (uint4*)(ws + 7876608);               // 6,144 B

    emission_kernel<<<(BB * SS) / 64, 256, 0, stream>>>(f, w, bias, trans, exem, Ebuf);
    chunk_kernel<<<BB * 32, 192, 0, stream>>>(exem, Ebuf, lengths, Qs, Lsc);
    finalize_kernel<<<BB, 64, 0, stream>>>(exem, trans, lengths, tags, Qs, Lsc, out);
}

// Round 10
// 116.998 us; speedup vs baseline: 1.7057x; 1.0734x over previous
//
#include <hip/hip_runtime.h>
#include <math.h>

#define BB 32
#define SS 512
#define HH 256
#define TT 48
#define START_IDX 46
#define STOP_IDX 47

typedef __attribute__((ext_vector_type(8))) short short8;
typedef __attribute__((ext_vector_type(4))) float floatx4;

__device__ __forceinline__ float rfl(float x) {
    return __int_as_float(__builtin_amdgcn_readfirstlane(__float_as_int(x)));
}
__device__ __forceinline__ unsigned int bf16_rne(float x) {
    const unsigned int u = __float_as_uint(x);
    return (u + 0x7fffu + ((u >> 16) & 1u)) >> 16;
}
__device__ __forceinline__ float bf2f(unsigned short h) {
    return __uint_as_float(((unsigned int)h) << 16);
}

// ---------------------------------------------------------------------------
// Kernel 1: exem = exp(f.w + b) via bf16 MFMA; block 0 also prebuilds the
//   E = exp(trans) B-frags into ws for the chunk kernel.
// ---------------------------------------------------------------------------
__global__ __launch_bounds__(256) void emission_kernel(
    const float* __restrict__ f, const float* __restrict__ w,
    const float* __restrict__ bias, const float* __restrict__ trans,
    unsigned short* __restrict__ exem, uint4* __restrict__ Ebuf)
{
    __shared__ __align__(16) char smem[50176];
    __shared__ float biaslds[TT];
    unsigned short* wb = (unsigned short*)smem;       // [256][50] bf16
    uint4* fragbuf = (uint4*)(smem + 25600);          // [24][64]
    float* fl = (float*)smem;                         // [64][132] (overlay)

    const int tid = threadIdx.x;

    if (blockIdx.x == 0 && tid < 64) {
        const int g = tid >> 4, cl = tid & 15;
#pragma unroll
        for (int kc = 0; kc < 2; ++kc)
#pragma unroll
            for (int nt = 0; nt < 3; ++nt) {
                unsigned int p[4];
#pragma unroll
                for (int h2 = 0; h2 < 4; ++h2) {
                    const int k = kc * 32 + g * 8 + 2 * h2;
                    const int n = nt * 16 + cl;
                    const float lo = (k     < TT) ? __expf(trans[k * TT + n])       : 0.f;
                    const float hi = (k + 1 < TT) ? __expf(trans[(k + 1) * TT + n]) : 0.f;
                    p[h2] = bf16_rne(lo) | (bf16_rne(hi) << 16);
                }
                Ebuf[(kc * 3 + nt) * 64 + tid] = make_uint4(p[0], p[1], p[2], p[3]);
            }
    }

    for (int idx = tid; idx < HH * TT; idx += 256) {
        const int r = idx / TT;
        const int c = idx - r * TT;
        wb[r * 50 + c] = (unsigned short)bf16_rne(w[idx]);
    }
    if (tid < TT) biaslds[tid] = bias[tid];
    __syncthreads();

    for (int idx = tid; idx < 24 * 64; idx += 256) {
        const int fb = idx >> 6;
        const int l  = idx & 63;
        const int kt = fb / 3;
        const int nt = fb - kt * 3;
        const int kbase = kt * 32 + (l >> 4) * 8;
        const int col   = nt * 16 + (l & 15);
        unsigned int p[4];
#pragma unroll
        for (int h2 = 0; h2 < 4; ++h2) {
            const unsigned int lo = wb[(kbase + 2 * h2)     * 50 + col];
            const unsigned int hi = wb[(kbase + 2 * h2 + 1) * 50 + col];
            p[h2] = lo | (hi << 16);
        }
        fragbuf[idx] = make_uint4(p[0], p[1], p[2], p[3]);
    }
    __syncthreads();

    const int lane = tid & 63, wv = tid >> 6, g = lane >> 4, cl = lane & 15;

    short8 Bf[24];
#pragma unroll
    for (int fb = 0; fb < 24; ++fb)
        Bf[fb] = __builtin_bit_cast(short8, fragbuf[fb * 64 + lane]);
    __syncthreads();   // frags in regs; smem free for f overlay

    const int row0 = blockIdx.x * 64;
    floatx4 acc0 = {0.f,0.f,0.f,0.f}, acc1 = {0.f,0.f,0.f,0.f}, acc2 = {0.f,0.f,0.f,0.f};

    const int lr = wv * 16 + cl;
#pragma unroll
    for (int h = 0; h < 2; ++h) {
#pragma unroll
        for (int it = 0; it < 8; ++it) {
            const int idx = tid + it * 256;
            const int r = idx >> 5, k4 = idx & 31;
            const float4 v = ((const float4*)f)[(size_t)(row0 + r) * 64 + h * 32 + k4];
            *(float4*)&fl[r * 132 + k4 * 4] = v;
        }
        __syncthreads();
#pragma unroll
        for (int kt = 0; kt < 4; ++kt) {
            const float4 v0 = *(const float4*)&fl[lr * 132 + kt * 32 + g * 8];
            const float4 v1 = *(const float4*)&fl[lr * 132 + kt * 32 + g * 8 + 4];
            const unsigned int a0 = bf16_rne(v0.x) | (bf16_rne(v0.y) << 16);
            const unsigned int a1 = bf16_rne(v0.z) | (bf16_rne(v0.w) << 16);
            const unsigned int a2 = bf16_rne(v1.x) | (bf16_rne(v1.y) << 16);
            const unsigned int a3 = bf16_rne(v1.z) | (bf16_rne(v1.w) << 16);
            const short8 Af = __builtin_bit_cast(short8, make_uint4(a0, a1, a2, a3));
            const int kg = h * 4 + kt;
            acc0 = __builtin_amdgcn_mfma_f32_16x16x32_bf16(Af, Bf[kg * 3 + 0], acc0, 0, 0, 0);
            acc1 = __builtin_amdgcn_mfma_f32_16x16x32_bf16(Af, Bf[kg * 3 + 1], acc1, 0, 0, 0);
            acc2 = __builtin_amdgcn_mfma_f32_16x16x32_bf16(Af, Bf[kg * 3 + 2], acc2, 0, 0, 0);
        }
        __syncthreads();
    }

    const int outrow0 = row0 + wv * 16 + g * 4;
    const int n = cl;
#pragma unroll
    for (int r = 0; r < 4; ++r) {
        unsigned short* e = exem + (size_t)(outrow0 + r) * TT;
        e[ 0 + n] = (unsigned short)bf16_rne(__expf(acc0[r] + biaslds[ 0 + n]));
        e[16 + n] = (unsigned short)bf16_rne(__expf(acc1[r] + biaslds[16 + n]));
        e[32 + n] = (unsigned short)bf16_rne(__expf(acc2[r] + biaslds[32 + n]));
    }
}

// ---------------------------------------------------------------------------
// Kernel 2: chunk products Q_c = PROD(D_t*E), 16 steps/chunk, rows split
//   16/wave across 3 waves, per-rowblock normalization at step 8.
// ---------------------------------------------------------------------------
__global__ __launch_bounds__(192) void chunk_kernel(
    const unsigned short* __restrict__ exem,   // [B*S, T] bf16
    const uint4* __restrict__ Ebuf,            // prebuilt E B-frags
    const int*   __restrict__ lengths,
    unsigned short* __restrict__ Qs,           // [B*32][48][64] bf16 (col-major Q)
    float* __restrict__ Ls3)                   // [B*32][3] per-rowblock logscale
{
    __shared__ __align__(8)  unsigned short ebuf[16 * TT];
    __shared__ __align__(16) unsigned short abuf[3][17 * 56];

    const int bc = blockIdx.x, b = bc >> 5, c = bc & 31;
    const int len = lengths[b];
    int nsteps = (len - 1) - (c << 4);
    if (nsteps <= 0) return;
    if (nsteps > 16) nsteps = 16;

    const int tid = threadIdx.x;
    const int rb = tid >> 6, l = tid & 63, g = l >> 4, cl = l & 15;

    {
        const unsigned int* src = (const unsigned int*)(exem + ((size_t)b * SS + (c << 4)) * TT);
        unsigned int* dst = (unsigned int*)ebuf;
        dst[tid] = src[tid];
        dst[tid + 192] = src[tid + 192];
    }

    uint4 Bf[2][3];
#pragma unroll
    for (int kc = 0; kc < 2; ++kc)
#pragma unroll
        for (int nt = 0; nt < 3; ++nt)
            Bf[kc][nt] = Ebuf[(kc * 3 + nt) * 64 + l];

    __syncthreads();

    floatx4 acc[3];
#pragma unroll
    for (int nt = 0; nt < 3; ++nt)
#pragma unroll
        for (int r = 0; r < 4; ++r)
            acc[nt][r] = (16 * rb + 4 * g + r == nt * 16 + cl) ? 1.f : 0.f;

    float ev[3];
#pragma unroll
    for (int nt = 0; nt < 3; ++nt) ev[nt] = bf2f(ebuf[nt * 16 + cl]);

    float Lrb = 0.f;
    unsigned short* aw = abuf[rb];

    for (int s = 0; s < nsteps; ++s) {
        float scale = 1.f;
        if (s == 8) {   // one normalization mid-chunk
            const float sig = rfl(acc[0][0]);
            Lrb = __logf(sig);
            scale = __builtin_amdgcn_rcpf(sig);
        }
        const float f0 = ev[0] * scale, f1 = ev[1] * scale, f2 = ev[2] * scale;
#pragma unroll
        for (int r = 0; r < 4; ++r) {
            const int rw = (4 * g + r) * 56;
            aw[rw +      cl] = (unsigned short)bf16_rne(acc[0][r] * f0);
            aw[rw + 16 + cl] = (unsigned short)bf16_rne(acc[1][r] * f1);
            aw[rw + 32 + cl] = (unsigned short)bf16_rne(acc[2][r] * f2);
        }
        if (s + 1 < nsteps) {
#pragma unroll
            for (int nt = 0; nt < 3; ++nt)
                ev[nt] = bf2f(ebuf[(s + 1) * TT + nt * 16 + cl]);
        }
        uint4 a0 = *(const uint4*)&aw[cl * 56 + g * 8];
        uint4 a1 = *(const uint4*)&aw[cl * 56 + 32 + g * 8];
        if (g >= 2) a1 = make_uint4(0, 0, 0, 0);   // k >= 48 pad
        const floatx4 z = {0.f, 0.f, 0.f, 0.f};
#pragma unroll
        for (int nt = 0; nt < 3; ++nt) {
            floatx4 d = __builtin_amdgcn_mfma_f32_16x16x32_bf16(
                __builtin_bit_cast(short8, a0), __builtin_bit_cast(short8, Bf[0][nt]), z, 0, 0, 0);
            d = __builtin_amdgcn_mfma_f32_16x16x32_bf16(
                __builtin_bit_cast(short8, a1), __builtin_bit_cast(short8, Bf[1][nt]), d, 0, 0, 0);
            acc[nt] = d;
        }
    }

    unsigned short* qb = Qs + (size_t)bc * (TT * 64);
#pragma unroll
    for (int nt = 0; nt < 3; ++nt) {
        const unsigned int lo = bf16_rne(acc[nt][0]) | (bf16_rne(acc[nt][1]) << 16);
        const unsigned int hi = bf16_rne(acc[nt][2]) | (bf16_rne(acc[nt][3]) << 16);
        *(uint2*)&qb[(nt * 16 + cl) * 64 + 16 * rb + 4 * g] = make_uint2(lo, hi);
    }
    if (l == 0) Ls3[bc * 3 + rb] = Lrb;
}

// ---------------------------------------------------------------------------
// Kernel 3: per-batch combine (serial MFMA matvecs, distance-1 prefetch)
//   + gold + output. Rowblock scales reconciled at the v-write.
// ---------------------------------------------------------------------------
__global__ __launch_bounds__(64) void finalize_kernel(
    const unsigned short* __restrict__ exem,
    const float* __restrict__ trans,
    const int*   __restrict__ lengths,
    const int*   __restrict__ tags,
    const unsigned short* __restrict__ Qs,
    const float* __restrict__ Ls3,
    float* __restrict__ out)
{
    __shared__ float tlds[TT * TT];
    __shared__ __align__(16) unsigned short vlds[64];
    __shared__ float Lsl[96];

    const int j = threadIdx.x, b = blockIdx.x, g = j >> 4, cl = j & 15;

    for (int idx = j; idx < TT * TT; idx += 64) tlds[idx] = trans[idx];

    const int len = lengths[b];
    const int nc = (len - 1 + 15) >> 4;
    for (int i = j; i < nc * 3; i += 64) Lsl[i] = Ls3[b * 96 + i];
    __builtin_amdgcn_wave_barrier();

    // gold path score
    float gold = 0.f;
    for (int s = j; s < len; s += 64) {
        const int tag  = tags[b * SS + s];
        const int from = (s == 0) ? START_IDX : tags[b * SS + s - 1];
        gold += __logf(bf2f(exem[((size_t)b * SS + s) * TT + tag])) + tlds[from * TT + tag];
    }
    gold += __shfl_xor(gold, 32); gold += __shfl_xor(gold, 16); gold += __shfl_xor(gold, 8);
    gold += __shfl_xor(gold, 4);  gold += __shfl_xor(gold, 2);  gold += __shfl_xor(gold, 1);

    // v init: E[START,:] with chunk-0 rowblock factors folded in
    const float R0 = Lsl[0];
    float vj = 0.f;
    if (j < TT) vj = __expf(tlds[START_IDX * TT + j]) * __expf(Lsl[j >> 4] - R0);
    vlds[j] = (unsigned short)bf16_rne(vj);   // j>=48 -> 0 (k-pad)
    float L = R0;

    const unsigned short* qbase = Qs + (size_t)(b * 32) * (TT * 64);
    floatx4 accn[3];
    float inv = 1.f;

    uint4 pB0[3], pB1[3];
#pragma unroll
    for (int nt = 0; nt < 3; ++nt) {
        pB0[nt] = *(const uint4*)&qbase[(nt * 16 + cl) * 64 + g * 8];
        pB1[nt] = *(const uint4*)&qbase[(nt * 16 + cl) * 64 + 32 + g * 8];
    }

    for (int cc = 0; cc < nc; ++cc) {
        uint4 B0[3], B1[3];
#pragma unroll
        for (int nt = 0; nt < 3; ++nt) { B0[nt] = pB0[nt]; B1[nt] = pB1[nt]; }

        const int cn = (cc + 1 < nc) ? cc + 1 : cc;
#pragma unroll
        for (int nt = 0; nt < 3; ++nt) {
            pB0[nt] = *(const uint4*)&qbase[(size_t)cn * TT * 64 + (nt * 16 + cl) * 64 + g * 8];
            pB1[nt] = *(const uint4*)&qbase[(size_t)cn * TT * 64 + (nt * 16 + cl) * 64 + 32 + g * 8];
        }
#pragma unroll
        for (int nt = 0; nt < 3; ++nt)
            if (g >= 2) B1[nt] = make_uint4(0, 0, 0, 0);

        const uint4 A0 = *(const uint4*)&vlds[g * 8];
        const uint4 A1 = *(const uint4*)&vlds[32 + g * 8];

        const floatx4 z = {0.f, 0.f, 0.f, 0.f};
#pragma unroll
        for (int nt = 0; nt < 3; ++nt) {
            floatx4 d = __builtin_amdgcn_mfma_f32_16x16x32_bf16(
                __builtin_bit_cast(short8, A0), __builtin_bit_cast(short8, B0[nt]), z, 0, 0, 0);
            d = __builtin_amdgcn_mfma_f32_16x16x32_bf16(
                __builtin_bit_cast(short8, A1), __builtin_bit_cast(short8, B1[nt]), d, 0, 0, 0);
            accn[nt] = d;
        }

        const float sig = rfl(accn[0][0]);   // > 0 always
        inv = __builtin_amdgcn_rcpf(sig);

        if (cc + 1 < nc) {
            const float Rn = Lsl[(cc + 1) * 3];
            const float fa0 = __expf(Lsl[(cc + 1) * 3 + 0] - Rn);
            const float fa1 = __expf(Lsl[(cc + 1) * 3 + 1] - Rn);
            const float fa2 = __expf(Lsl[(cc + 1) * 3 + 2] - Rn);
            L += __logf(sig) + Rn;
            if (j < 16) {   // row 0 of result: lanes 0..15, reg 0
                vlds[ 0 + j] = (unsigned short)bf16_rne(accn[0][0] * inv * fa0);
                vlds[16 + j] = (unsigned short)bf16_rne(accn[1][0] * inv * fa1);
                vlds[32 + j] = (unsigned short)bf16_rne(accn[2][0] * inv * fa2);
            }
        } else {
            L += __logf(sig);
        }
    }

    // terminal: sum_n v[n] * exem[len-1][n] * exp(trans[n][STOP])
    float term = 0.f;
    if (j < 16) {
        const size_t erow = ((size_t)b * SS + (len - 1)) * TT;
#pragma unroll
        for (int nt = 0; nt < 3; ++nt) {
            const int col = nt * 16 + j;
            term += accn[nt][0] * inv * bf2f(exem[erow + col])
                    * __expf(tlds[col * TT + STOP_IDX]);
        }
    }
    term += __shfl_xor(term, 32); term += __shfl_xor(term, 16); term += __shfl_xor(term, 8);
    term += __shfl_xor(term, 4);  term += __shfl_xor(term, 2);  term += __shfl_xor(term, 1);

    if (j == 0) {
        const float all_paths = __logf(term) + L;
        const int last = tags[b * SS + len - 1];
        out[b] = all_paths - (gold + tlds[last * TT + STOP_IDX]);
    }
}

// ---------------------------------------------------------------------------
extern "C" void kernel_launch(void* const* d_in, const int* in_sizes, int n_in,
                              void* d_out, int out_size, void* d_ws, size_t ws_size,
                              hipStream_t stream) {
    const float* f       = (const float*)d_in[0];
    const float* w       = (const float*)d_in[1];
    const float* bias    = (const float*)d_in[2];
    const float* trans   = (const float*)d_in[3];
    const int*   lengths = (const int*)d_in[4];
    const int*   tags    = (const int*)d_in[5];
    float*       out     = (float*)d_out;

    // ws: exem bf16 | Qs bf16 | Ls3 f32 | Ebuf
    char* ws = (char*)d_ws;
    unsigned short* exem = (unsigned short*)ws;                  // 1,572,864 B
    unsigned short* Qs   = (unsigned short*)(ws + 1572864);      // 6,291,456 B
    float*          Lsc  = (float*)(ws + 7864320);               // 12,288 B
    uint4*          Ebuf = (uint4*)(ws + 7876608);               // 6,144 B

    emission_kernel<<<(BB * SS) / 64, 256, 0, stream>>>(f, w, bias, trans, exem, Ebuf);
    chunk_kernel<<<BB * 32, 192, 0, stream>>>(exem, Ebuf, lengths, Qs, Lsc);
    finalize_kernel<<<BB, 64, 0, stream>>>(exem, trans, lengths, tags, Qs, Lsc, out);
}